// Round 1
// baseline (1562.203 us; speedup 1.0000x reference)
//
#include <hip/hip_runtime.h>

#define N_NODES 100000
#define N_EDGES 600000
#define DIM 128
#define NUM_RELS 8

// ---------------------------------------------------------------------------
// cnt[i][r] = number of edges of type r with dst==i   (float, exact for small counts)
__global__ __launch_bounds__(256) void count_kernel(const int* __restrict__ ei,
                                                    const int* __restrict__ et,
                                                    float* __restrict__ cnt) {
    int e = blockIdx.x * 256 + threadIdx.x;
    if (e < N_EDGES) {
        int dst = ei[N_EDGES + e];
        int r   = et[e];
        unsafeAtomicAdd(&cnt[(size_t)dst * NUM_RELS + r], 1.0f);
    }
}

// ---------------------------------------------------------------------------
// Big path: acc[dst][r][:] += x[src][:]    acc layout [N][8][128]
// One wave (64 lanes) per edge, float2 per lane.
__global__ __launch_bounds__(256) void scatter_big(const int* __restrict__ ei,
                                                   const int* __restrict__ et,
                                                   const float* __restrict__ x,
                                                   float* __restrict__ acc) {
    int e    = blockIdx.x * 4 + (threadIdx.x >> 6);
    int lane = threadIdx.x & 63;
    if (e < N_EDGES) {
        int src = ei[e];
        int dst = ei[N_EDGES + e];
        int r   = et[e];
        const float2 v = *reinterpret_cast<const float2*>(&x[(size_t)src * DIM + lane * 2]);
        float* p = &acc[(size_t)dst * (NUM_RELS * DIM) + r * DIM + lane * 2];
        unsafeAtomicAdd(p,     v.x);
        unsafeAtomicAdd(p + 1, v.y);
    }
}

// Small path: only edges of type `rel`, acc layout [N][128]
__global__ __launch_bounds__(256) void scatter_rel(const int* __restrict__ ei,
                                                   const int* __restrict__ et,
                                                   const float* __restrict__ x,
                                                   float* __restrict__ acc, int rel) {
    int e    = blockIdx.x * 4 + (threadIdx.x >> 6);
    int lane = threadIdx.x & 63;
    if (e < N_EDGES) {
        int r = et[e];
        if (r != rel) return;
        int src = ei[e];
        int dst = ei[N_EDGES + e];
        const float2 v = *reinterpret_cast<const float2*>(&x[(size_t)src * DIM + lane * 2]);
        float* p = &acc[(size_t)dst * DIM + lane * 2];
        unsafeAtomicAdd(p,     v.x);
        unsafeAtomicAdd(p + 1, v.y);
    }
}

// ---------------------------------------------------------------------------
// Generic chunked GEMM:
//   chunk 0   : out[i][:]  (=|+=) x[i] @ W_root (+ bias)
//   chunk c>0 : out[i][:] +=      (acc_row(i,c-1) / max(cnt[i][c-1],1)) @ W[c-1]
// acc element: acc[row*accRowStride + (c-1)*accChunkStride + k]
// Block: 32 nodes x 128 dims; thread computes 4x4; W chunk (64KB) + A tile (16KB) in LDS.
__global__ __launch_bounds__(256) void rgcn_gemm(
    const float* __restrict__ x, const float* __restrict__ acc,
    const float* __restrict__ cnt, const float* __restrict__ W,
    const float* __restrict__ W_root, const float* __restrict__ bias,
    float* __restrict__ out, int accRowStride, int accChunkStride,
    int cStart, int cEnd, int accumulate) {
    __shared__ float Wt[DIM * DIM];   // [k][d] row-major, 64KB
    __shared__ float At[32 * DIM];    // [n][k] row-major, 16KB
    const int t = threadIdx.x;
    const int node0 = blockIdx.x * 32;
    const int d0 = (t & 31) * 4;
    const int n0 = (t >> 5) * 4;

    float accv[4][4];
#pragma unroll
    for (int j = 0; j < 4; ++j)
#pragma unroll
        for (int i = 0; i < 4; ++i) accv[j][i] = 0.0f;

    for (int c = cStart; c < cEnd; ++c) {
        const float* Wsrc = (c == 0) ? W_root : (W + (size_t)(c - 1) * DIM * DIM);
#pragma unroll
        for (int i = 0; i < 64; ++i) Wt[t + i * 256] = Wsrc[t + i * 256];

#pragma unroll
        for (int i = 0; i < 16; ++i) {
            int lin = t + i * 256;
            int n = lin >> 7;       // 0..31
            int k = lin & 127;
            float v;
            if (c == 0) {
                v = x[(size_t)(node0 + n) * DIM + k];
            } else {
                float cv  = cnt[(size_t)(node0 + n) * NUM_RELS + (c - 1)];
                float inv = 1.0f / fmaxf(cv, 1.0f);
                v = acc[(size_t)(node0 + n) * accRowStride + (size_t)(c - 1) * accChunkStride + k] * inv;
            }
            At[n * DIM + k] = v;
        }
        __syncthreads();

#pragma unroll 4
        for (int k = 0; k < DIM; ++k) {
            float4 wv = *reinterpret_cast<const float4*>(&Wt[k * DIM + d0]);
            float a0 = At[(n0 + 0) * DIM + k];
            float a1 = At[(n0 + 1) * DIM + k];
            float a2 = At[(n0 + 2) * DIM + k];
            float a3 = At[(n0 + 3) * DIM + k];
            accv[0][0] += a0 * wv.x; accv[0][1] += a0 * wv.y; accv[0][2] += a0 * wv.z; accv[0][3] += a0 * wv.w;
            accv[1][0] += a1 * wv.x; accv[1][1] += a1 * wv.y; accv[1][2] += a1 * wv.z; accv[1][3] += a1 * wv.w;
            accv[2][0] += a2 * wv.x; accv[2][1] += a2 * wv.y; accv[2][2] += a2 * wv.z; accv[2][3] += a2 * wv.w;
            accv[3][0] += a3 * wv.x; accv[3][1] += a3 * wv.y; accv[3][2] += a3 * wv.z; accv[3][3] += a3 * wv.w;
        }
        __syncthreads();
    }

    float4 bv = make_float4(0.f, 0.f, 0.f, 0.f);
    if (bias) bv = *reinterpret_cast<const float4*>(&bias[d0]);
#pragma unroll
    for (int j = 0; j < 4; ++j) {
        float4* po = reinterpret_cast<float4*>(&out[(size_t)(node0 + n0 + j) * DIM + d0]);
        float4 o;
        o.x = accv[j][0] + bv.x;
        o.y = accv[j][1] + bv.y;
        o.z = accv[j][2] + bv.z;
        o.w = accv[j][3] + bv.w;
        if (accumulate) {
            float4 prev = *po;
            o.x += prev.x; o.y += prev.y; o.z += prev.z; o.w += prev.w;
        }
        *po = o;
    }
}

// ---------------------------------------------------------------------------
extern "C" void kernel_launch(void* const* d_in, const int* in_sizes, int n_in,
                              void* d_out, int out_size, void* d_ws, size_t ws_size,
                              hipStream_t stream) {
    const float* x      = (const float*)d_in[0];
    const float* W      = (const float*)d_in[1];
    const float* W_root = (const float*)d_in[2];
    const float* bias   = (const float*)d_in[3];
    const int*   ei     = (const int*)d_in[4];   // [2][E]: row0=src, row1=dst
    const int*   et     = (const int*)d_in[5];   // [E]
    float* out = (float*)d_out;

    const size_t cnt_bytes   = (size_t)N_NODES * NUM_RELS * sizeof(float);          // 3.2 MB
    const size_t acc_big_b   = (size_t)N_NODES * NUM_RELS * DIM * sizeof(float);    // 409.6 MB
    const size_t acc_small_b = (size_t)N_NODES * DIM * sizeof(float);               // 51.2 MB

    float* cnt = (float*)d_ws;
    float* acc = (float*)((char*)d_ws + cnt_bytes);   // cnt_bytes is 16B-aligned

    if (ws_size >= cnt_bytes + acc_big_b) {
        // ---- big path: one scatter over [N][8][128], one fused 9-chunk GEMM
        hipMemsetAsync(d_ws, 0, cnt_bytes + acc_big_b, stream);
        count_kernel<<<(N_EDGES + 255) / 256, 256, 0, stream>>>(ei, et, cnt);
        scatter_big<<<N_EDGES / 4, 256, 0, stream>>>(ei, et, x, acc);
        rgcn_gemm<<<N_NODES / 32, 256, 0, stream>>>(x, acc, cnt, W, W_root, bias, out,
                                                    NUM_RELS * DIM, DIM, 0, 9, 0);
    } else {
        // ---- small path: per-relation acc [N][128], 8 scatter+GEMM-accumulate rounds
        hipMemsetAsync(d_ws, 0, cnt_bytes, stream);
        count_kernel<<<(N_EDGES + 255) / 256, 256, 0, stream>>>(ei, et, cnt);
        rgcn_gemm<<<N_NODES / 32, 256, 0, stream>>>(x, nullptr, cnt, W, W_root, bias, out,
                                                    0, 0, 0, 1, 0);
        for (int r = 0; r < NUM_RELS; ++r) {
            hipMemsetAsync(acc, 0, acc_small_b, stream);
            scatter_rel<<<N_EDGES / 4, 256, 0, stream>>>(ei, et, x, acc, r);
            rgcn_gemm<<<N_NODES / 32, 256, 0, stream>>>(x, acc, cnt, W, W_root, nullptr, out,
                                                        DIM, 0, r + 1, r + 2, 1);
        }
    }
}

// Round 2
// 368.644 us; speedup vs baseline: 4.2377x; 4.2377x over previous
//
#include <hip/hip_runtime.h>

#define N_NODES 100000
#define N_EDGES 600000
#define DIM 128
#define NUM_RELS 8

typedef unsigned int u32;
typedef __attribute__((ext_vector_type(8))) short bf16x8;   // 8 bf16 = 4 VGPR (MFMA A/B frag)
typedef __attribute__((ext_vector_type(4))) float f32x4;    // MFMA C/D frag

// round-nearest-even f32 -> bf16, packed pair (lo -> low 16, hi -> high 16)
__device__ __forceinline__ u32 pack2_bf16_rn(float lo, float hi) {
    u32 a = __float_as_uint(lo);
    u32 b = __float_as_uint(hi);
    a += 0x7fffu + ((a >> 16) & 1u);
    b += 0x7fffu + ((b >> 16) & 1u);
    return (a >> 16) | (b & 0xffff0000u);
}

// ---------------------------------------------------------------------------
// x (f32 [N][128]) -> x_bf (bf16 [N][128]); 8 elems / thread
__global__ __launch_bounds__(256) void convert_x(const float* __restrict__ x,
                                                 uint4* __restrict__ x_bf) {
    int t = blockIdx.x * 256 + threadIdx.x;            // one uint4 (8 bf16) per thread
    if (t >= N_NODES * DIM / 8) return;
    const float4* p = reinterpret_cast<const float4*>(x) + (size_t)t * 2;
    float4 v0 = p[0], v1 = p[1];
    uint4 o;
    o.x = pack2_bf16_rn(v0.x, v0.y);
    o.y = pack2_bf16_rn(v0.z, v0.w);
    o.z = pack2_bf16_rn(v1.x, v1.y);
    o.w = pack2_bf16_rn(v1.z, v1.w);
    x_bf[t] = o;
}

// ---------------------------------------------------------------------------
// W chunks (c=0: W_root, c=1..8: W[c-1]) -> Wt, transposed to [col][k] bf16 and
// XOR-swizzled in 16B blocks: ushort index = c*16384 + n*128 + ((k>>3)^(n&7))*8 + (k&7)
// so a linear LDS copy + swizzled ds_read_b128 is bank-conflict-free.
__global__ __launch_bounds__(256) void transpose_w(const float* __restrict__ W,
                                                   const float* __restrict__ W_root,
                                                   unsigned short* __restrict__ Wt) {
    int t = blockIdx.x * 256 + threadIdx.x;            // elem over 9*128*128
    if (t >= 9 * DIM * DIM) return;
    int c  = t >> 14;
    int kn = t & 16383;
    int k = kn >> 7, n = kn & 127;
    float v = (c == 0) ? W_root[kn] : W[(size_t)(c - 1) * DIM * DIM + kn];
    u32 b = __float_as_uint(v);
    b += 0x7fffu + ((b >> 16) & 1u);
    size_t off = (size_t)c * 16384 + n * 128 + (((k >> 3) ^ (n & 7)) << 3) + (k & 7);
    Wt[off] = (unsigned short)(b >> 16);
}

// ---------------------------------------------------------------------------
__device__ __forceinline__ void atomic_pk_add_bf16(u32* addr, u32 val) {
    asm volatile("global_atomic_pk_add_bf16 %0, %1, off" :: "v"(addr), "v"(val) : "memory");
}

// One wave per edge: acc[dst-lo][r][:] += x_bf[src][:] (packed bf16 atomics),
// count fused on lane 0. acc layout: [rows][8 rel][128 bf16] (256B per (node,rel)).
__global__ __launch_bounds__(256) void scatter_edges(const int* __restrict__ ei,
                                                     const int* __restrict__ et,
                                                     const u32* __restrict__ x_bf,
                                                     u32* __restrict__ acc,
                                                     float* __restrict__ cnt,
                                                     int lo, int hi) {
    int e    = blockIdx.x * 4 + (threadIdx.x >> 6);
    int lane = threadIdx.x & 63;
    if (e >= N_EDGES) return;
    int dst = ei[N_EDGES + e];
    if (dst < lo || dst >= hi) return;                 // wave-uniform
    int src = ei[e];
    int r   = et[e];
    if (lane == 0) unsafeAtomicAdd(&cnt[(size_t)dst * NUM_RELS + r], 1.0f);
    u32 v = x_bf[(size_t)src * 64 + lane];             // 2 bf16
    atomic_pk_add_bf16(acc + (((size_t)(dst - lo) * NUM_RELS + r) << 6) + lane, v);
}

// ---------------------------------------------------------------------------
// apply per-row scale to a raw bf16x8 frag (unpack->f32, *s, repack RNE)
__device__ __forceinline__ bf16x8 scale_frag(uint4 v, float s) {
    union { uint4 u; bf16x8 h; } r;
    u32 in[4] = { v.x, v.y, v.z, v.w };
    u32 o[4];
#pragma unroll
    for (int i = 0; i < 4; ++i) {
        u32 w = in[i];
        float lo = __uint_as_float(w << 16) * s;
        float hi = __uint_as_float(w & 0xffff0000u) * s;
        o[i] = pack2_bf16_rn(lo, hi);
    }
    r.u = make_uint4(o[0], o[1], o[2], o[3]);
    return r.h;
}

// Fused 9-chunk bf16 MFMA GEMM:
//   out[i][:] = x_bf[i] @ Wt[0] + bias + sum_c (acc_mean(i,c-1)) @ Wt[c]
// Block: 256 thr = 4 waves; tile M=128 x N=128; wave owns 32 rows x 128 cols
// (2 M-frags x 8 N-frags of 16x16). A-frags straight from global (single-use),
// B (Wt chunk, 32KB) staged in LDS pre-swizzled.
__global__ __launch_bounds__(256) void rgcn_mfma(
    const uint4* __restrict__ x_bf,   // [N][16] uint4
    const uint4* __restrict__ acc,    // [rows][8][16] uint4
    const float* __restrict__ cnt,    // [N][8]
    const uint4* __restrict__ Wt,     // 9 * 2048 uint4, swizzled
    const float* __restrict__ bias,
    float* __restrict__ out,
    int lo, int hi) {
    __shared__ uint4 Wlds[2048];                       // 32 KB: [col 0..127][kb 0..15]
    const int tid  = threadIdx.x;
    const int w    = tid >> 6;
    const int lane = tid & 63;
    const int g = lane >> 4, m = lane & 15;
    const int node0 = lo + blockIdx.x * 128;

    f32x4 accv[2][8];
#pragma unroll
    for (int mi = 0; mi < 2; ++mi)
#pragma unroll
        for (int ni = 0; ni < 8; ++ni) accv[mi][ni] = (f32x4)0.0f;

    int rowA[2];                                       // lane's A rows (2 M-frags)
    rowA[0] = node0 + w * 32 + m;
    rowA[1] = rowA[0] + 16;
    int rowC[2] = { rowA[0] < hi - 1 ? rowA[0] : hi - 1,
                    rowA[1] < hi - 1 ? rowA[1] : hi - 1 };

    for (int c = 0; c < 9; ++c) {
        __syncthreads();                               // prev chunk's Wlds reads done
        const uint4* src = Wt + (size_t)c * 2048;
#pragma unroll
        for (int i = 0; i < 8; ++i)
            Wlds[i * 256 + tid] = src[i * 256 + tid];

        // A-frags for this chunk: araw[mi][ks], 16B per frag, global gather
        uint4 araw[2][4];
        float s[2];
        if (c == 0) {
#pragma unroll
            for (int mi = 0; mi < 2; ++mi) {
                s[mi] = 1.0f;
                const uint4* a = x_bf + (size_t)rowC[mi] * 16;
#pragma unroll
                for (int ks = 0; ks < 4; ++ks) araw[mi][ks] = a[ks * 4 + g];
            }
        } else {
#pragma unroll
            for (int mi = 0; mi < 2; ++mi) {
                float cv = cnt[(size_t)rowC[mi] * NUM_RELS + (c - 1)];
                s[mi] = __builtin_amdgcn_rcpf(fmaxf(cv, 1.0f));
                const uint4* a = acc + ((size_t)(rowC[mi] - lo) * NUM_RELS + (c - 1)) * 16;
#pragma unroll
                for (int ks = 0; ks < 4; ++ks) araw[mi][ks] = a[ks * 4 + g];
            }
        }

        bf16x8 afrag[2][4];
#pragma unroll
        for (int mi = 0; mi < 2; ++mi)
#pragma unroll
            for (int ks = 0; ks < 4; ++ks) afrag[mi][ks] = scale_frag(araw[mi][ks], s[mi]);

        __syncthreads();                               // Wlds staged

#pragma unroll
        for (int ks = 0; ks < 4; ++ks) {
#pragma unroll
            for (int ni = 0; ni < 8; ++ni) {
                // B frag: col = ni*16+m, kb = ks*4+g, swizzled kb^(m&7)
                uint4 braw = Wlds[(ni * 16 + m) * 16 + ((ks * 4 + g) ^ (m & 7))];
                union { uint4 u; bf16x8 h; } bb; bb.u = braw;
                accv[0][ni] = __builtin_amdgcn_mfma_f32_16x16x32_bf16(afrag[0][ks], bb.h, accv[0][ni], 0, 0, 0);
                accv[1][ni] = __builtin_amdgcn_mfma_f32_16x16x32_bf16(afrag[1][ks], bb.h, accv[1][ni], 0, 0, 0);
            }
        }
    }

    // epilogue: + bias, store f32. C/D layout: col=lane&15, row=(lane>>4)*4+reg
#pragma unroll
    for (int ni = 0; ni < 8; ++ni) {
        float bv = bias[ni * 16 + m];
#pragma unroll
        for (int mi = 0; mi < 2; ++mi) {
            int rbase = node0 + w * 32 + mi * 16 + g * 4;
#pragma unroll
            for (int j = 0; j < 4; ++j) {
                int rr = rbase + j;
                if (rr < hi) out[(size_t)rr * DIM + ni * 16 + m] = accv[mi][ni][j] + bv;
            }
        }
    }
}

// ---------------------------------------------------------------------------
extern "C" void kernel_launch(void* const* d_in, const int* in_sizes, int n_in,
                              void* d_out, int out_size, void* d_ws, size_t ws_size,
                              hipStream_t stream) {
    const float* x      = (const float*)d_in[0];
    const float* W      = (const float*)d_in[1];
    const float* W_root = (const float*)d_in[2];
    const float* bias   = (const float*)d_in[3];
    const int*   ei     = (const int*)d_in[4];   // [2][E]
    const int*   et     = (const int*)d_in[5];   // [E]
    float* out = (float*)d_out;

    char* ws = (char*)d_ws;
    uint4*          x_bf = (uint4*)ws;                                   // 25,600,000 B
    unsigned short* Wt   = (unsigned short*)(ws + 25600000);             //    294,912 B
    float*          cnt  = (float*)(ws + 25600000 + 294912);             //  3,200,000 B
    u32*            acc  = (u32*)(ws + 29094912);                        // rest

    const size_t head = 29094912;
    int NC = 64;
    for (int nc = 1; nc <= 64; ++nc) {
        size_t rpc = (N_NODES + nc - 1) / nc;
        if (head + rpc * 2048 <= ws_size) { NC = nc; break; }
    }
    const int rpc = (N_NODES + NC - 1) / NC;

    convert_x<<<(N_NODES * DIM / 8 + 255) / 256, 256, 0, stream>>>(x, x_bf);
    transpose_w<<<(9 * DIM * DIM + 255) / 256, 256, 0, stream>>>(W, W_root, Wt);
    hipMemsetAsync(cnt, 0, 3200000, stream);

    for (int nc = 0; nc < NC; ++nc) {
        int lo = nc * rpc;
        int hi = lo + rpc < N_NODES ? lo + rpc : N_NODES;
        if (lo >= hi) break;
        hipMemsetAsync(acc, 0, (size_t)(hi - lo) * 2048, stream);
        scatter_edges<<<(N_EDGES + 3) / 4, 256, 0, stream>>>(ei, et, (const u32*)x_bf, acc, cnt, lo, hi);
        rgcn_mfma<<<(hi - lo + 127) / 128, 256, 0, stream>>>(x_bf, (const uint4*)acc, cnt, (const uint4*)Wt,
                                                             bias, out, lo, hi);
    }
}